// Round 2
// baseline (1067.485 us; speedup 1.0000x reference)
//
#include <hip/hip_runtime.h>

#define SCALE 0.08838834764831845f

constexpr int B_    = 32;
constexpr int H_    = 32;
constexpr int KVH_  = 8;
constexpr int G_    = 4;     // H / KVH
constexpr int D_    = 128;
constexpr int BS_   = 128;   // cache block size
constexpr int MAXB_ = 32;    // max blocks per seq
constexpr int NSPLIT = 64;
constexpr int CHUNK  = 4096 / NSPLIT;   // 64 positions per split (half a cache block)
constexpr int LPAD   = 36;              // logit2 row stride in floats (bank-spread)

// ---------------------------------------------------------------------------
// Kernel 1: workgroup = (b, split). The 8 half-waves each own ONE kv head, so
// per position the workgroup reads the full [KVH][D] row = 4 KB CONTIGUOUS,
// and across the 64-position chunk it streams a contiguous 256 KB region of K
// (then of V). This restores DRAM row locality that the previous
// one-kv-head-per-workgroup layout destroyed (512 B used out of every 4 KB).
//
// Phase A: half-wave hw computes scores for heads hw*4..hw*4+3 over its 64
//   positions; 32-lane dot (masks 4/8/16) + crossed 2-stage finish puts
//   score g in lane (l32&3)==g (15 shuffles total, vs 20).
// Phase B: softmax per head row (8 threads/row) on logit2[pos][head].
// Phase C: half-wave hw streams V rows for kv=hw, weights broadcast as one
//   float4 per position; acc written straight to part_o (no cross-reduce).
// ---------------------------------------------------------------------------
__global__ __launch_bounds__(256) void attn_partial(
    const float* __restrict__ q,        // [B,H,D]
    const float* __restrict__ kc,       // [NB,BS,KVH,D]
    const float* __restrict__ vc,       // [NB,BS,KVH,D]
    const int*   __restrict__ bt,       // [B,MAXB]
    const int*   __restrict__ ctxl,     // [B]
    float*       __restrict__ part_o,   // [B,KVH,NSPLIT,G,D]
    float*       __restrict__ part_ml)  // [B,KVH,NSPLIT,G,2]
{
    const int bid   = blockIdx.x;
    const int split = bid & (NSPLIT - 1);
    const int b     = bid >> 6;
    const int tid   = threadIdx.x;

    const int ctx = ctxl[b];
    int clen = ctx - split * CHUNK;
    if (clen > CHUNK) clen = CHUNK;
    if (clen <= 0) {
        if (tid < KVH_ * G_) {
            const int kv = tid >> 2, g = tid & 3;
            const size_t mb =
                ((size_t)(b * KVH_ + kv) * NSPLIT + split) * (G_ * 2) + g * 2;
            part_ml[mb + 0] = -__builtin_inff();
            part_ml[mb + 1] = 0.f;
        }
        return;
    }

    __shared__ __align__(16) float logit2[CHUNK][LPAD];  // [pos][head], ~9 KB

    const int hw  = tid >> 5;   // half-wave id == kv head
    const int l32 = tid & 31;

    const int blk  = bt[b * MAXB_ + (split >> 1)];
    const int poff = (split & 1) * CHUNK;
    const float* kbase =
        kc + (((size_t)blk * BS_ + poff) * KVH_ + hw) * D_ + l32 * 4;

    // Q fragments: lane l32 holds q[head][l32*4 .. +3] for the 4 heads of hw.
    float4 qf[G_];
#pragma unroll
    for (int g = 0; g < G_; g++) {
        qf[g] = *(const float4*)(q + ((size_t)b * H_ + hw * G_ + g) * D_ + l32 * 4);
        qf[g].x *= SCALE; qf[g].y *= SCALE; qf[g].z *= SCALE; qf[g].w *= SCALE;
    }

    // ---------------- Phase A: scores ----------------
#pragma unroll 2
    for (int p = 0; p < clen; ++p) {
        const float4 k4 = *(const float4*)(kbase + (size_t)p * (KVH_ * D_));
        float s0 = k4.x*qf[0].x + k4.y*qf[0].y + k4.z*qf[0].z + k4.w*qf[0].w;
        float s1 = k4.x*qf[1].x + k4.y*qf[1].y + k4.z*qf[1].z + k4.w*qf[1].w;
        float s2 = k4.x*qf[2].x + k4.y*qf[2].y + k4.z*qf[2].z + k4.w*qf[2].w;
        float s3 = k4.x*qf[3].x + k4.y*qf[3].y + k4.z*qf[3].z + k4.w*qf[3].w;
#pragma unroll
        for (int m = 4; m <= 16; m <<= 1) {
            s0 += __shfl_xor(s0, m, 64);
            s1 += __shfl_xor(s1, m, 64);
            s2 += __shfl_xor(s2, m, 64);
            s3 += __shfl_xor(s3, m, 64);
        }
        // crossed finish over lane bits 0..1: lane (l32&3)==g gets score g
        const bool o1 = (l32 & 1) != 0, o2 = (l32 & 2) != 0;
        float a01 = o1 ? s0 : s1;  float r01 = __shfl_xor(a01, 1, 64);
        float uA  = (o1 ? s1 : s0) + r01;
        float a23 = o1 ? s2 : s3;  float r23 = __shfl_xor(a23, 1, 64);
        float uB  = (o1 ? s3 : s2) + r23;
        float v   = o2 ? uA : uB;  float rv  = __shfl_xor(v, 2, 64);
        float fin = (o2 ? uB : uA) + rv;
        if (l32 < 4) logit2[p][hw * G_ + l32] = fin;
    }
    __syncthreads();

    // ---------------- Phase B: softmax per head (8 threads / row) ---------
    {
        const int h = tid >> 3, ln8 = tid & 7;
        float m = -__builtin_inff();
        for (int i = ln8; i < clen; i += 8) m = fmaxf(m, logit2[i][h]);
#pragma unroll
        for (int mk = 4; mk >= 1; mk >>= 1)
            m = fmaxf(m, __shfl_xor(m, mk, 64));
        float l = 0.f;
        for (int i = ln8; i < clen; i += 8) {
            float pv = __expf(logit2[i][h] - m);
            logit2[i][h] = pv;
            l += pv;
        }
#pragma unroll
        for (int mk = 4; mk >= 1; mk >>= 1) l += __shfl_xor(l, mk, 64);
        if (ln8 == 0) {
            const size_t mb =
                ((size_t)(b * KVH_ + (h >> 2)) * NSPLIT + split) * (G_ * 2) +
                (h & 3) * 2;
            part_ml[mb + 0] = m;
            part_ml[mb + 1] = l;
        }
    }
    __syncthreads();

    // ---------------- Phase C: o = P . V (direct, no cross-reduce) --------
    const float* vbase =
        vc + (((size_t)blk * BS_ + poff) * KVH_ + hw) * D_ + l32 * 4;
    float4 a0 = {0,0,0,0}, a1 = {0,0,0,0}, a2 = {0,0,0,0}, a3 = {0,0,0,0};
#pragma unroll 4
    for (int p = 0; p < clen; ++p) {
        const float4 v4 = *(const float4*)(vbase + (size_t)p * (KVH_ * D_));
        const float4 w4 = *(const float4*)(&logit2[p][hw * G_]);  // broadcast
        a0.x += w4.x * v4.x; a0.y += w4.x * v4.y; a0.z += w4.x * v4.z; a0.w += w4.x * v4.w;
        a1.x += w4.y * v4.x; a1.y += w4.y * v4.y; a1.z += w4.y * v4.z; a1.w += w4.y * v4.w;
        a2.x += w4.z * v4.x; a2.y += w4.z * v4.y; a2.z += w4.z * v4.z; a2.w += w4.z * v4.w;
        a3.x += w4.w * v4.x; a3.y += w4.w * v4.y; a3.z += w4.w * v4.z; a3.w += w4.w * v4.w;
    }
    const size_t ob =
        ((size_t)(b * KVH_ + hw) * NSPLIT + split) * (G_ * D_) + l32 * 4;
    *(float4*)(part_o + ob + 0 * D_) = a0;
    *(float4*)(part_o + ob + 1 * D_) = a1;
    *(float4*)(part_o + ob + 2 * D_) = a2;
    *(float4*)(part_o + ob + 3 * D_) = a3;
}

// ---------------------------------------------------------------------------
// Kernel 2: merge NSPLIT partials per (b, kvh). Wave g loads (m,l) for its
// head with one lane per split, butterfly-reduces M and L, then 256 threads
// accumulate the weighted partial outputs.
// ---------------------------------------------------------------------------
__global__ __launch_bounds__(256) void attn_reduce(
    const float* __restrict__ part_o,
    const float* __restrict__ part_ml,
    float*       __restrict__ out)  // [B,H,D]
{
    const int bid = blockIdx.x;  // b*KVH + kv
    const int tid = threadIdx.x;

    __shared__ float sc[G_][NSPLIT];
    __shared__ float Ls[G_];

    {
        const int g = tid >> 6, s = tid & 63;  // wave g, lane = split
        const size_t base = ((size_t)bid * NSPLIT + s) * (G_ * 2) + g * 2;
        const float mv = part_ml[base + 0];
        const float lv = part_ml[base + 1];
        float key = (lv > 0.f) ? mv : -__builtin_inff();
#pragma unroll
        for (int mk = 32; mk >= 1; mk >>= 1)
            key = fmaxf(key, __shfl_xor(key, mk, 64));
        const float f = (lv > 0.f) ? __expf(mv - key) : 0.f;
        sc[g][s] = f;
        float fl = f * lv;
#pragma unroll
        for (int mk = 32; mk >= 1; mk >>= 1) fl += __shfl_xor(fl, mk, 64);
        if (s == 0) Ls[g] = fl;
    }
    __syncthreads();

    for (int e = tid; e < G_ * D_; e += 256) {
        const int g = e >> 7;  // uniform per wave
        float a = 0.f;
#pragma unroll 4
        for (int s = 0; s < NSPLIT; s++) {
            const float f = sc[g][s];
            if (f != 0.f)  // also guards poisoned part_o of empty splits
                a += f * part_o[((size_t)bid * NSPLIT + s) * (G_ * D_) + e];
        }
        out[(size_t)bid * (G_ * D_) + e] = a / Ls[g];
    }
}

extern "C" void kernel_launch(void* const* d_in, const int* in_sizes, int n_in,
                              void* d_out, int out_size, void* d_ws, size_t ws_size,
                              hipStream_t stream) {
    const float* q   = (const float*)d_in[0];
    const float* kc  = (const float*)d_in[1];
    const float* vc  = (const float*)d_in[2];
    const int*   bt  = (const int*)d_in[3];
    const int*   ctx = (const int*)d_in[4];
    float* out = (float*)d_out;

    float* part_o  = (float*)d_ws;  // B*KVH*NSPLIT*G*D floats = 33.5 MB
    float* part_ml = part_o + (size_t)B_ * KVH_ * NSPLIT * G_ * D_;  // +0.5 MB

    attn_partial<<<B_ * NSPLIT, 256, 0, stream>>>(q, kc, vc, bt, ctx,
                                                  part_o, part_ml);
    attn_reduce<<<B_ * KVH_, 256, 0, stream>>>(part_o, part_ml, out);
}